// Round 2
// baseline (125.148 us; speedup 1.0000x reference)
//
#include <hip/hip_runtime.h>
#include <hip/hip_bf16.h>
#include <math.h>

typedef __attribute__((ext_vector_type(8))) short bf16x8;
typedef __attribute__((ext_vector_type(4))) float f32x4;
typedef __attribute__((ext_vector_type(2))) float f32x2;

constexpr int B_ = 4096;
constexpr int N_ = 8192;   // 2B rows
constexpr int D_ = 128;
constexpr float INV_T = 2.0f;              // 1/temperature
constexpr float E2C = 7.38905609893065f;   // exp(2) — diagonal self-sim term

// ---------------- Kernel A: L2-normalize rows -> bf16 Z; zero denom & out ----
__global__ __launch_bounds__(256) void nrm_kernel(const float* __restrict__ ei,
                                                  const float* __restrict__ ej,
                                                  __hip_bfloat16* __restrict__ zb,
                                                  float* __restrict__ denom,
                                                  float* __restrict__ out) {
    int wid  = (blockIdx.x * blockDim.x + threadIdx.x) >> 6;  // one wave per row
    int lane = threadIdx.x & 63;
    if (wid >= N_) return;
    const float* src = (wid < B_) ? (ei + (size_t)wid * D_)
                                  : (ej + (size_t)(wid - B_) * D_);
    f32x2 v = *(const f32x2*)(src + lane * 2);
    float ss = v.x * v.x + v.y * v.y;
    #pragma unroll
    for (int m = 1; m < 64; m <<= 1) ss += __shfl_xor(ss, m);
    float rn = rsqrtf(ss);
    __hip_bfloat162 o;
    o.x = __float2bfloat16(v.x * rn);
    o.y = __float2bfloat16(v.y * rn);
    *(__hip_bfloat162*)(zb + (size_t)wid * D_ + lane * 2) = o;
    if (lane == 0) denom[wid] = 0.0f;
    if (wid == 0 && lane == 0) out[0] = 0.0f;
}

// ---------------- Kernel P: positives pos[k] = <z_i[k], z_j[k]> in fp32 ------
__global__ __launch_bounds__(256) void pos_kernel(const float* __restrict__ ei,
                                                  const float* __restrict__ ej,
                                                  float* __restrict__ pos) {
    int wid  = (blockIdx.x * blockDim.x + threadIdx.x) >> 6;  // one wave per pair
    int lane = threadIdx.x & 63;
    if (wid >= B_) return;
    f32x2 a = *(const f32x2*)(ei + (size_t)wid * D_ + lane * 2);
    f32x2 b = *(const f32x2*)(ej + (size_t)wid * D_ + lane * 2);
    float dot = a.x * b.x + a.y * b.y;
    float na  = a.x * a.x + a.y * a.y;
    float nb  = b.x * b.x + b.y * b.y;
    #pragma unroll
    for (int m = 1; m < 64; m <<= 1) {
        dot += __shfl_xor(dot, m);
        na  += __shfl_xor(na, m);
        nb  += __shfl_xor(nb, m);
    }
    if (lane == 0) pos[wid] = dot * rsqrtf(na * nb);
}

// ---------------- Kernel B: fused sim = Z Z^T, exp(2*sim), row sums ----------
// Block: 256 threads = 4 waves, each wave owns 32 rows (2 m-tiles of 16).
// Grid: (N_/128) x NJ column splits. B-fragments loaded straight from global
// (Z is 2 MB -> L2-resident on every XCD). No LDS, no barriers.
constexpr int NJ = 16;
constexpr int BLK_ROWS = 128;
constexpr int JCHUNK = N_ / NJ;  // 512 columns per block

__global__ __launch_bounds__(256) void simsum_kernel(const __hip_bfloat16* __restrict__ zb,
                                                     float* __restrict__ denom) {
    int lane = threadIdx.x & 63;
    int wave = threadIdx.x >> 6;                       // 0..3
    int r0   = blockIdx.x * BLK_ROWS + wave * 32;      // wave's first row
    int jbase = blockIdx.y * JCHUNK;
    int g  = lane >> 4;                                // k-group 0..3
    int lm = lane & 15;

    const short* Z = (const short*)zb;

    // A fragments: rows r0 + t*16 + lm, k = s*32 + g*8 .. +8  (16B each)
    bf16x8 a[2][4];
    #pragma unroll
    for (int t = 0; t < 2; ++t)
        #pragma unroll
        for (int s = 0; s < 4; ++s)
            a[t][s] = *(const bf16x8*)(Z + (size_t)(r0 + t * 16 + lm) * D_ + s * 32 + g * 8);

    f32x4 rs0 = {0.f, 0.f, 0.f, 0.f};
    f32x4 rs1 = {0.f, 0.f, 0.f, 0.f};

    const short* pB = Z + (size_t)(jbase + lm) * D_ + g * 8;
    for (int jt = 0; jt < JCHUNK / 16; ++jt) {
        bf16x8 b0 = *(const bf16x8*)(pB);
        bf16x8 b1 = *(const bf16x8*)(pB + 32);
        bf16x8 b2 = *(const bf16x8*)(pB + 64);
        bf16x8 b3 = *(const bf16x8*)(pB + 96);
        f32x4 acc0 = {0.f, 0.f, 0.f, 0.f};
        f32x4 acc1 = {0.f, 0.f, 0.f, 0.f};
        acc0 = __builtin_amdgcn_mfma_f32_16x16x32_bf16(a[0][0], b0, acc0, 0, 0, 0);
        acc1 = __builtin_amdgcn_mfma_f32_16x16x32_bf16(a[1][0], b0, acc1, 0, 0, 0);
        acc0 = __builtin_amdgcn_mfma_f32_16x16x32_bf16(a[0][1], b1, acc0, 0, 0, 0);
        acc1 = __builtin_amdgcn_mfma_f32_16x16x32_bf16(a[1][1], b1, acc1, 0, 0, 0);
        acc0 = __builtin_amdgcn_mfma_f32_16x16x32_bf16(a[0][2], b2, acc0, 0, 0, 0);
        acc1 = __builtin_amdgcn_mfma_f32_16x16x32_bf16(a[1][2], b2, acc1, 0, 0, 0);
        acc0 = __builtin_amdgcn_mfma_f32_16x16x32_bf16(a[0][3], b3, acc0, 0, 0, 0);
        acc1 = __builtin_amdgcn_mfma_f32_16x16x32_bf16(a[1][3], b3, acc1, 0, 0, 0);
        #pragma unroll
        for (int r = 0; r < 4; ++r) {
            rs0[r] += __expf(INV_T * acc0[r]);
            rs1[r] += __expf(INV_T * acc1[r]);
        }
        pB += 16 * D_;
    }

    // reduce partial row sums across the 16 column-lanes (low 4 lane bits)
    #pragma unroll
    for (int m = 1; m < 16; m <<= 1) {
        #pragma unroll
        for (int r = 0; r < 4; ++r) {
            rs0[r] += __shfl_xor(rs0[r], m);
            rs1[r] += __shfl_xor(rs1[r], m);
        }
    }
    if (lm == 0) {
        #pragma unroll
        for (int r = 0; r < 4; ++r) {
            atomicAdd(&denom[r0 + g * 4 + r],      rs0[r]);
            atomicAdd(&denom[r0 + 16 + g * 4 + r], rs1[r]);
        }
    }
}

// ---------------- Kernel C: loss = mean(log(denom - e^2) - 2*pos) ------------
__global__ __launch_bounds__(256) void loss_kernel(const float* __restrict__ denom,
                                                   const float* __restrict__ pos,
                                                   float* __restrict__ out) {
    int tid = threadIdx.x;
    int k   = blockIdx.x * 256 + tid;
    float d = denom[k] - E2C;
    float v = __logf(d) - pos[k & (B_ - 1)] * INV_T;
    #pragma unroll
    for (int m = 1; m < 64; m <<= 1) v += __shfl_xor(v, m);
    __shared__ float part[4];
    if ((tid & 63) == 0) part[tid >> 6] = v;
    __syncthreads();
    if (tid == 0)
        atomicAdd(out, (part[0] + part[1] + part[2] + part[3]) * (1.0f / N_));
}

// ---------------- launch ------------------------------------------------------
extern "C" void kernel_launch(void* const* d_in, const int* in_sizes, int n_in,
                              void* d_out, int out_size, void* d_ws, size_t ws_size,
                              hipStream_t stream) {
    const float* ei = (const float*)d_in[0];
    const float* ej = (const float*)d_in[1];
    float* out = (float*)d_out;

    __hip_bfloat16* zb = (__hip_bfloat16*)d_ws;                    // 2 MB
    float* denom = (float*)((char*)d_ws + (size_t)N_ * D_ * 2);    // 32 KB
    float* pos   = denom + N_;                                     // 16 KB

    // A: normalize -> bf16 Z, zero denom & out
    nrm_kernel<<<dim3(N_ / 4), dim3(256), 0, stream>>>(ei, ej, zb, denom, out);
    // P: positives
    pos_kernel<<<dim3(B_ / 4), dim3(256), 0, stream>>>(ei, ej, pos);
    // B: fused sim/exp/rowsum
    simsum_kernel<<<dim3(N_ / BLK_ROWS, NJ), dim3(256), 0, stream>>>(zb, denom);
    // C: final loss
    loss_kernel<<<dim3(N_ / 256), dim3(256), 0, stream>>>(denom, pos, out);
}